// Round 7
// baseline (628.572 us; speedup 1.0000x reference)
//
#include <hip/hip_runtime.h>

#define THREADS 256
#define KC 32
#define NC 4

// ---- bf16 helpers ----
__device__ inline ushort f2bf(float v) {
    union { float f; unsigned u; } a; a.f = v;
    unsigned r = a.u + 0x7fff + ((a.u >> 16) & 1);
    return (ushort)(r >> 16);
}
__device__ inline float bf2f(ushort u) {
    union { unsigned u; float f; } a; a.u = (unsigned)u << 16; return a.f;
}
__device__ inline float bflo(unsigned v) {
    union { unsigned u; float f; } a; a.u = v << 16; return a.f;
}
__device__ inline float bfhi(unsigned v) {
    union { unsigned u; float f; } a; a.u = v & 0xffff0000u; return a.f;
}

// wave-uniform row base (csr index j is wave-uniform -> SGPR addressing)
__device__ inline const ushort* rowp(const ushort* H, int s) {
    return H + ((size_t)(unsigned)__builtin_amdgcn_readfirstlane(s) << 6);
}

// ---------- degree per (chunk,dst) + per-edge rank ----------
__global__ void k_deg_c(const int* __restrict__ src, const int* __restrict__ dst,
                        int* __restrict__ degc, int* __restrict__ rank,
                        int E, int n, int ch) {
    int e = blockIdx.x * blockDim.x + threadIdx.x;
    if (e >= E) return;
    int c = (unsigned)src[e] / (unsigned)ch;           // 0..NC-1
    rank[e] = atomicAdd(&degc[(size_t)c * n + dst[e]], 1);
}

__global__ void k_dinv4(const int* __restrict__ degc, float* __restrict__ dinv, int n) {
    int i = blockIdx.x * blockDim.x + threadIdx.x;
    if (i >= n) return;
    int d = 0;
    #pragma unroll
    for (int c = 0; c < NC; ++c) d += degc[(size_t)c * n + i];
    dinv[i] = rsqrtf((float)d + 1.0f);
}

// ---------- 3-level exclusive scan over M = NC*n elements ----------
__global__ void k_bsum(const int* __restrict__ a, int* __restrict__ bsum, int m) {
    __shared__ int s[THREADS];
    int i = blockIdx.x * THREADS + threadIdx.x;
    s[threadIdx.x] = (i < m) ? a[i] : 0;
    __syncthreads();
    for (int o = THREADS / 2; o; o >>= 1) {
        if (threadIdx.x < o) s[threadIdx.x] += s[threadIdx.x + o];
        __syncthreads();
    }
    if (threadIdx.x == 0) bsum[blockIdx.x] = s[0];
}

// single block of 512; nb <= 512
__global__ void k_bscan(int* __restrict__ bsum, int nb) {
    __shared__ int s[512];
    int v = (threadIdx.x < nb) ? bsum[threadIdx.x] : 0;
    s[threadIdx.x] = v;
    __syncthreads();
    for (int o = 1; o < 512; o <<= 1) {
        int t = (threadIdx.x >= (unsigned)o) ? s[threadIdx.x - o] : 0;
        __syncthreads();
        s[threadIdx.x] += t;
        __syncthreads();
    }
    if (threadIdx.x < nb) bsum[threadIdx.x] = s[threadIdx.x] - v;  // exclusive
}

// B1 -> global exclusive scan of B1, using exclusive block bases B2
__global__ void k_scanadd(int* __restrict__ B1, const int* __restrict__ B2, int m) {
    __shared__ int s[THREADS];
    int i = blockIdx.x * THREADS + threadIdx.x;
    int v = (i < m) ? B1[i] : 0;
    s[threadIdx.x] = v;
    __syncthreads();
    for (int o = 1; o < THREADS; o <<= 1) {
        int t = (threadIdx.x >= (unsigned)o) ? s[threadIdx.x - o] : 0;
        __syncthreads();
        s[threadIdx.x] += t;
        __syncthreads();
    }
    if (i < m) B1[i] = B2[blockIdx.x] + s[threadIdx.x] - v;
}

__global__ void k_offsets4(const int* __restrict__ degc, const int* __restrict__ B1,
                           int* __restrict__ off4, int m, int E) {
    __shared__ int s[THREADS];
    int i = blockIdx.x * THREADS + threadIdx.x;
    int v = (i < m) ? degc[i] : 0;
    s[threadIdx.x] = v;
    __syncthreads();
    for (int o = 1; o < THREADS; o <<= 1) {
        int t = (threadIdx.x >= (unsigned)o) ? s[threadIdx.x - o] : 0;
        __syncthreads();
        s[threadIdx.x] += t;
        __syncthreads();
    }
    if (i < m) {
        off4[i] = B1[blockIdx.x] + s[threadIdx.x] - v;
        if (i == m - 1) off4[m] = E;
    }
}

// one fire-and-forget scattered 4B store per edge; no atomics
__global__ void k_bucket4(const int* __restrict__ src, const int* __restrict__ dst,
                          const int* __restrict__ rank, const int* __restrict__ off4,
                          int* __restrict__ csr_src, int E, int n, int ch) {
    int e = blockIdx.x * blockDim.x + threadIdx.x;
    if (e >= E) return;
    int s = src[e];
    int c = (unsigned)s / (unsigned)ch;
    csr_src[off4[(size_t)c * n + dst[e]] + rank[e]] = s;
}

// ---------- tiled GEMM (fp32 X): C'[r,c] = (X@W)[r,c] * dinv[r] -> bf16 ----------
__global__ __launch_bounds__(THREADS) void
k_gemm_f32(const float* __restrict__ X, const float* __restrict__ W,
           const float* __restrict__ dinv, ushort* __restrict__ C, int n, int fin) {
    __shared__ float Xs[KC][68];
    __shared__ float Ws[KC][64];
    int tid = threadIdx.x;
    int r0  = blockIdx.x * 64;
    int tx4 = (tid & 15) * 4;
    int ty4 = (tid >> 4) * 4;
    int sxr = tid >> 2, sxk = (tid & 3) * 4;
    int swk = tid >> 4, swc = (tid & 15) * 4;
    int xrow = r0 + sxr; if (xrow >= n) xrow = n - 1;
    const float* xptr = X + (size_t)xrow * fin;
    float4 acc0 = {0,0,0,0}, acc1 = {0,0,0,0}, acc2 = {0,0,0,0}, acc3 = {0,0,0,0};
    for (int kc = 0; kc < fin; kc += KC) {
        float4 xa = *(const float4*)(xptr + kc + sxk);
        float4 xb = *(const float4*)(xptr + kc + 16 + sxk);
        float4 wa = *(const float4*)(W + (size_t)(kc + swk) * 64 + swc);
        float4 wb = *(const float4*)(W + (size_t)(kc + swk + 16) * 64 + swc);
        __syncthreads();
        Xs[sxk + 0][sxr] = xa.x; Xs[sxk + 1][sxr] = xa.y;
        Xs[sxk + 2][sxr] = xa.z; Xs[sxk + 3][sxr] = xa.w;
        Xs[16 + sxk + 0][sxr] = xb.x; Xs[16 + sxk + 1][sxr] = xb.y;
        Xs[16 + sxk + 2][sxr] = xb.z; Xs[16 + sxk + 3][sxr] = xb.w;
        *(float4*)&Ws[swk][swc]      = wa;
        *(float4*)&Ws[swk + 16][swc] = wb;
        __syncthreads();
        #pragma unroll 8
        for (int k = 0; k < KC; ++k) {
            float4 a = *(const float4*)&Xs[k][ty4];
            float4 b = *(const float4*)&Ws[k][tx4];
            acc0.x = fmaf(a.x, b.x, acc0.x); acc0.y = fmaf(a.x, b.y, acc0.y);
            acc0.z = fmaf(a.x, b.z, acc0.z); acc0.w = fmaf(a.x, b.w, acc0.w);
            acc1.x = fmaf(a.y, b.x, acc1.x); acc1.y = fmaf(a.y, b.y, acc1.y);
            acc1.z = fmaf(a.y, b.z, acc1.z); acc1.w = fmaf(a.y, b.w, acc1.w);
            acc2.x = fmaf(a.z, b.x, acc2.x); acc2.y = fmaf(a.z, b.y, acc2.y);
            acc2.z = fmaf(a.z, b.z, acc2.z); acc2.w = fmaf(a.z, b.w, acc2.w);
            acc3.x = fmaf(a.w, b.x, acc3.x); acc3.y = fmaf(a.w, b.y, acc3.y);
            acc3.z = fmaf(a.w, b.z, acc3.z); acc3.w = fmaf(a.w, b.w, acc3.w);
        }
    }
    int row = r0 + ty4;
    #pragma unroll
    for (int r = 0; r < 4; ++r) {
        if (row + r >= n) break;
        float dn = dinv[row + r];
        float4 a = r == 0 ? acc0 : r == 1 ? acc1 : r == 2 ? acc2 : acc3;
        ushort4 o;
        o.x = f2bf(a.x * dn); o.y = f2bf(a.y * dn);
        o.z = f2bf(a.z * dn); o.w = f2bf(a.w * dn);
        *(ushort4*)(C + (size_t)(row + r) * 64 + tx4) = o;
    }
}

// ---------- tiled GEMM (bf16 X): C' = (X@W)*dinv -> bf16 ----------
__global__ __launch_bounds__(THREADS) void
k_gemm_bf16(const ushort* __restrict__ X, const float* __restrict__ W,
            const float* __restrict__ dinv, ushort* __restrict__ C, int n, int fin) {
    __shared__ float Xs[KC][68];
    __shared__ float Ws[KC][64];
    int tid = threadIdx.x;
    int r0  = blockIdx.x * 64;
    int tx4 = (tid & 15) * 4;
    int ty4 = (tid >> 4) * 4;
    int sxr = tid >> 2, sk8 = (tid & 3) * 8;
    int swk = tid >> 4, swc = (tid & 15) * 4;
    int xrow = r0 + sxr; if (xrow >= n) xrow = n - 1;
    const ushort* xptr = X + (size_t)xrow * fin;
    float4 acc0 = {0,0,0,0}, acc1 = {0,0,0,0}, acc2 = {0,0,0,0}, acc3 = {0,0,0,0};
    for (int kc = 0; kc < fin; kc += KC) {
        uint4 xv = *(const uint4*)(xptr + kc + sk8);
        float4 wa = *(const float4*)(W + (size_t)(kc + swk) * 64 + swc);
        float4 wb = *(const float4*)(W + (size_t)(kc + swk + 16) * 64 + swc);
        __syncthreads();
        Xs[sk8 + 0][sxr] = bflo(xv.x); Xs[sk8 + 1][sxr] = bfhi(xv.x);
        Xs[sk8 + 2][sxr] = bflo(xv.y); Xs[sk8 + 3][sxr] = bfhi(xv.y);
        Xs[sk8 + 4][sxr] = bflo(xv.z); Xs[sk8 + 5][sxr] = bfhi(xv.z);
        Xs[sk8 + 6][sxr] = bflo(xv.w); Xs[sk8 + 7][sxr] = bfhi(xv.w);
        *(float4*)&Ws[swk][swc]      = wa;
        *(float4*)&Ws[swk + 16][swc] = wb;
        __syncthreads();
        #pragma unroll 8
        for (int k = 0; k < KC; ++k) {
            float4 a = *(const float4*)&Xs[k][ty4];
            float4 b = *(const float4*)&Ws[k][tx4];
            acc0.x = fmaf(a.x, b.x, acc0.x); acc0.y = fmaf(a.x, b.y, acc0.y);
            acc0.z = fmaf(a.x, b.z, acc0.z); acc0.w = fmaf(a.x, b.w, acc0.w);
            acc1.x = fmaf(a.y, b.x, acc1.x); acc1.y = fmaf(a.y, b.y, acc1.y);
            acc1.z = fmaf(a.y, b.z, acc1.z); acc1.w = fmaf(a.y, b.w, acc1.w);
            acc2.x = fmaf(a.z, b.x, acc2.x); acc2.y = fmaf(a.z, b.y, acc2.y);
            acc2.z = fmaf(a.z, b.z, acc2.z); acc2.w = fmaf(a.z, b.w, acc2.w);
            acc3.x = fmaf(a.w, b.x, acc3.x); acc3.y = fmaf(a.w, b.y, acc3.y);
            acc3.z = fmaf(a.w, b.z, acc3.z); acc3.w = fmaf(a.w, b.w, acc3.w);
        }
    }
    int row = r0 + ty4;
    #pragma unroll
    for (int r = 0; r < 4; ++r) {
        if (row + r >= n) break;
        float dn = dinv[row + r];
        float4 a = r == 0 ? acc0 : r == 1 ? acc1 : r == 2 ? acc2 : acc3;
        ushort4 o;
        o.x = f2bf(a.x * dn); o.y = f2bf(a.y * dn);
        o.z = f2bf(a.z * dn); o.w = f2bf(a.w * dn);
        *(ushort4*)(C + (size_t)(row + r) * 64 + tx4) = o;
    }
}

// ---------- phase-segment sum (rows pre-scaled by dinv[src]) ----------
__device__ inline float seg_sum(const ushort* __restrict__ H,
                                const int* __restrict__ csr_src,
                                int j, int end, int c) {
    float a0 = 0.f, a1 = 0.f, a2 = 0.f, a3 = 0.f;
    for (; j + 3 < end; j += 4) {
        int s0 = __builtin_nontemporal_load(&csr_src[j]);
        int s1 = __builtin_nontemporal_load(&csr_src[j + 1]);
        int s2 = __builtin_nontemporal_load(&csr_src[j + 2]);
        int s3 = __builtin_nontemporal_load(&csr_src[j + 3]);
        float h0 = bf2f(rowp(H, s0)[c]);
        float h1 = bf2f(rowp(H, s1)[c]);
        float h2 = bf2f(rowp(H, s2)[c]);
        float h3 = bf2f(rowp(H, s3)[c]);
        a0 += h0; a1 += h1; a2 += h2; a3 += h3;
    }
    for (; j < end; ++j) {
        int s = __builtin_nontemporal_load(&csr_src[j]);
        a0 += bf2f(rowp(H, s)[c]);
    }
    return (a0 + a1) + (a2 + a3);
}

// phase 0: acc = self + sum(chunk0)
__global__ void k_gath_first(const ushort* __restrict__ H, const int* __restrict__ csr_src,
                             const int* __restrict__ off4, float* __restrict__ acc, int n) {
    int t = blockIdx.x * blockDim.x + threadIdx.x;
    int node = t >> 6;
    if (node >= n) return;
    int c = t & 63;
    int j = off4[node], end = off4[node + 1];
    float a = bf2f(H[(size_t)node * 64 + c]) + seg_sum(H, csr_src, j, end, c);
    __builtin_nontemporal_store(a, &acc[t]);
}

// phases 1..NC-2: acc += sum(chunk p)
__global__ void k_gath_mid(const ushort* __restrict__ H, const int* __restrict__ csr_src,
                           const int* __restrict__ off4, float* __restrict__ acc,
                           int n, int phase) {
    int t = blockIdx.x * blockDim.x + threadIdx.x;
    int node = t >> 6;
    if (node >= n) return;
    int c = t & 63;
    size_t base = (size_t)phase * n + node;
    int j = off4[base], end = off4[base + 1];
    float a = __builtin_nontemporal_load(&acc[t]) + seg_sum(H, csr_src, j, end, c);
    __builtin_nontemporal_store(a, &acc[t]);
}

// last phase, layer 1: relu(dn*(acc+sum)+b) -> bf16
__global__ void k_gath_last_l1(const ushort* __restrict__ H, const int* __restrict__ csr_src,
                               const int* __restrict__ off4, const float* __restrict__ acc,
                               const float* __restrict__ dinv, const float* __restrict__ b,
                               ushort* __restrict__ out, int n, int phase) {
    int t = blockIdx.x * blockDim.x + threadIdx.x;
    int node = t >> 6;
    if (node >= n) return;
    int c = t & 63;
    size_t base = (size_t)phase * n + node;
    int j = off4[base], end = off4[base + 1];
    float a = __builtin_nontemporal_load(&acc[t]) + seg_sum(H, csr_src, j, end, c);
    float v = a * dinv[node] + b[c];
    out[t] = f2bf(v > 0.f ? v : 0.f);
}

// last phase, layer 2: relu + fused FC(64->16) + 16-dim pool scatter
__global__ void k_gath_last_fc(const ushort* __restrict__ H, const int* __restrict__ csr_src,
                               const int* __restrict__ off4, const float* __restrict__ acc,
                               const float* __restrict__ dinv, const float* __restrict__ b,
                               const float* __restrict__ Wfc, const int* __restrict__ dict,
                               float* __restrict__ pool16, int n, int phase) {
    __shared__ float wt[16 * 65];
    __shared__ float hrow[4][64];
    int tid = threadIdx.x;
    for (int i = tid; i < 64 * 16; i += THREADS) {
        int cc = i >> 4, r = i & 15;
        wt[r * 65 + cc] = Wfc[i];
    }
    int t = blockIdx.x * blockDim.x + tid;
    int node = t >> 6;
    int c = t & 63;
    int nl = tid >> 6;
    float v = 0.f;
    if (node < n) {
        size_t base = (size_t)phase * n + node;
        int j = off4[base], end = off4[base + 1];
        float a = __builtin_nontemporal_load(&acc[t]) + seg_sum(H, csr_src, j, end, c);
        float hv = a * dinv[node] + b[c];
        v = hv > 0.f ? hv : 0.f;
    }
    hrow[nl][c] = v;
    __syncthreads();
    int g = c >> 4, r = c & 15;
    float p = 0.f;
    #pragma unroll
    for (int i = 0; i < 16; ++i) {
        int cc = g * 16 + i;
        p = fmaf(hrow[nl][cc], wt[r * 65 + cc], p);
    }
    p += __shfl_xor(p, 16);
    p += __shfl_xor(p, 32);
    if (node < n && g == 0)
        atomicAdd(&pool16[(size_t)dict[node] * 16 + r], p);
}

__global__ void k_cnt(const int* __restrict__ dict, float* __restrict__ cnt, int n) {
    int i = blockIdx.x * blockDim.x + threadIdx.x;
    if (i < n) atomicAdd(&cnt[dict[i]], 1.0f);
}

// ---------- mean + bias + log_softmax over 16 classes ----------
__global__ void k_final16(const float* __restrict__ pool16, const float* __restrict__ cnt,
                          const float* __restrict__ bfc, float* __restrict__ out, int n) {
    int tid = threadIdx.x;
    int nl = tid >> 4, lane = tid & 15;
    int node = blockIdx.x * 16 + nl;
    if (node >= n) return;
    float inv = 1.0f / fmaxf(cnt[node], 1.0f);
    float acc = pool16[(size_t)node * 16 + lane] * inv + bfc[lane];
    float m = acc;
    for (int o = 8; o; o >>= 1) m = fmaxf(m, __shfl_xor(m, o, 16));
    float ex = __expf(acc - m);
    float s = ex;
    for (int o = 8; o; o >>= 1) s += __shfl_xor(s, o, 16);
    out[(size_t)node * 16 + lane] = acc - m - __logf(s);
}

extern "C" void kernel_launch(void* const* d_in, const int* in_sizes, int n_in,
                              void* d_out, int out_size, void* d_ws, size_t ws_size,
                              hipStream_t stream) {
    const float* x    = (const float*)d_in[0];
    const int*   ei   = (const int*)d_in[1];
    const int*   dict = (const int*)d_in[2];
    const float* W1   = (const float*)d_in[3];
    const float* b1   = (const float*)d_in[4];
    const float* W2   = (const float*)d_in[5];
    const float* b2   = (const float*)d_in[6];
    const float* Wfc  = (const float*)d_in[7];
    const float* bfc  = (const float*)d_in[8];

    const int N  = in_sizes[2];          // 100000
    const int E  = in_sizes[1] / 2;      // 1600000
    const int IN = in_sizes[0] / N;      // 128
    const int CH = (N + NC - 1) / NC;    // 25000 nodes/chunk (~3.2 MB bf16)
    const int M  = NC * N;               // 400000 scan elements
    const int* src = ei;
    const int* dst = ei + E;

    // workspace layout (~68 MB): pool16 overlays rank (disjoint lifetimes)
    ushort* bufA   = (ushort*)d_ws;                    // N*64 bf16
    ushort* bufB   = bufA + (size_t)N * 64;            // N*64 bf16
    float*  acc    = (float*)(bufB + (size_t)N * 64);  // N*64 f32
    float*  dinv   = acc + (size_t)N * 64;             // N
    int*    degc   = (int*)(dinv + N);                 // NC*N
    float*  cnt    = (float*)(degc + M);               // N
    int*    off4   = (int*)(cnt + N);                  // NC*N + 1
    int*    B1     = off4 + M + 1;                     // 2048
    int*    B2     = B1 + 2048;                        // 512
    int*    rank   = B2 + 512;                         // E
    int*    csr    = rank + E;                         // E
    float*  pool16 = (float*)rank;                     // N*16 (== E) overlay

    const int gN    = (N + THREADS - 1) / THREADS;          // 391
    const int gE    = (E + THREADS - 1) / THREADS;          // 6250
    const int gNE   = (N * 64 + THREADS - 1) / THREADS;     // 25000
    const int gM    = (M + THREADS - 1) / THREADS;          // 1563
    const int gM2   = (gM + THREADS - 1) / THREADS;         // 7
    const int gTile = (N + 63) / 64;                        // 1563
    const int gRows = (N + 15) / 16;                        // 6250

    // chunked CSR build (once; reused by both layers)
    hipMemsetAsync(degc, 0, (size_t)M * sizeof(int), stream);
    hipMemsetAsync(cnt, 0, (size_t)N * sizeof(float), stream);
    k_deg_c<<<gE, THREADS, 0, stream>>>(src, dst, degc, rank, E, N, CH);
    k_dinv4<<<gN, THREADS, 0, stream>>>(degc, dinv, N);
    k_bsum<<<gM, THREADS, 0, stream>>>(degc, B1, M);
    k_bsum<<<gM2, THREADS, 0, stream>>>(B1, B2, gM);
    k_bscan<<<1, 512, 0, stream>>>(B2, gM2);
    k_scanadd<<<gM2, THREADS, 0, stream>>>(B1, B2, gM);
    k_offsets4<<<gM, THREADS, 0, stream>>>(degc, B1, off4, M, E);
    k_bucket4<<<gE, THREADS, 0, stream>>>(src, dst, rank, off4, csr, E, N, CH);
    hipMemsetAsync(pool16, 0, (size_t)N * 16 * sizeof(float), stream);  // after rank's last use

    // layer 1: A = bf16((x@W1)*dinv) ; phased gather -> B = bf16 h1
    k_gemm_f32<<<gTile, THREADS, 0, stream>>>(x, W1, dinv, bufA, N, IN);
    k_gath_first<<<gNE, THREADS, 0, stream>>>(bufA, csr, off4, acc, N);
    for (int p = 1; p < NC - 1; ++p)
        k_gath_mid<<<gNE, THREADS, 0, stream>>>(bufA, csr, off4, acc, N, p);
    k_gath_last_l1<<<gNE, THREADS, 0, stream>>>(bufA, csr, off4, acc, dinv, b1,
                                                bufB, N, NC - 1);

    // layer 2: A = bf16((B@W2)*dinv) ; phased gather + fused FC + pool
    k_gemm_bf16<<<gTile, THREADS, 0, stream>>>(bufB, W2, dinv, bufA, N, 64);
    k_gath_first<<<gNE, THREADS, 0, stream>>>(bufA, csr, off4, acc, N);
    for (int p = 1; p < NC - 1; ++p)
        k_gath_mid<<<gNE, THREADS, 0, stream>>>(bufA, csr, off4, acc, N, p);
    k_gath_last_fc<<<gNE, THREADS, 0, stream>>>(bufA, csr, off4, acc, dinv, b2, Wfc,
                                                dict, pool16, N, NC - 1);
    k_cnt<<<gN, THREADS, 0, stream>>>(dict, cnt, N);

    // mean + bias + log_softmax
    k_final16<<<gRows, THREADS, 0, stream>>>(pool16, cnt, bfc, (float*)d_out, N);
}

// Round 8
// 381.304 us; speedup vs baseline: 1.6485x; 1.6485x over previous
//
#include <hip/hip_runtime.h>

#define THREADS 256
#define KC 32

// ---- bf16 helpers ----
__device__ inline ushort f2bf(float v) {
    union { float f; unsigned u; } a; a.f = v;
    unsigned r = a.u + 0x7fff + ((a.u >> 16) & 1);
    return (ushort)(r >> 16);
}
__device__ inline float bflo(unsigned v) {
    union { unsigned u; float f; } a; a.u = v << 16; return a.f;
}
__device__ inline float bfhi(unsigned v) {
    union { unsigned u; float f; } a; a.u = v & 0xffff0000u; return a.f;
}

// ---------- degree + per-edge rank ----------
__global__ void k_deg(const int* __restrict__ dst, int* __restrict__ deg,
                      int* __restrict__ rank, int E) {
    int e = blockIdx.x * blockDim.x + threadIdx.x;
    if (e < E) rank[e] = atomicAdd(&deg[dst[e]], 1);
}

// ---------- CSR build: block sums -> scan -> offsets(+dinv) -> bucket ----------
__global__ void k_bsum(const int* __restrict__ deg, int* __restrict__ bsum, int n) {
    __shared__ int s[THREADS];
    int i = blockIdx.x * THREADS + threadIdx.x;
    s[threadIdx.x] = (i < n) ? deg[i] : 0;
    __syncthreads();
    for (int o = THREADS / 2; o; o >>= 1) {
        if (threadIdx.x < o) s[threadIdx.x] += s[threadIdx.x + o];
        __syncthreads();
    }
    if (threadIdx.x == 0) bsum[blockIdx.x] = s[0];
}

// single block of 512; nb <= 512 (nb = 391 here)
__global__ void k_bscan(int* __restrict__ bsum, int nb) {
    __shared__ int s[512];
    int v = (threadIdx.x < nb) ? bsum[threadIdx.x] : 0;
    s[threadIdx.x] = v;
    __syncthreads();
    for (int o = 1; o < 512; o <<= 1) {
        int t = (threadIdx.x >= (unsigned)o) ? s[threadIdx.x - o] : 0;
        __syncthreads();
        s[threadIdx.x] += t;
        __syncthreads();
    }
    if (threadIdx.x < nb) bsum[threadIdx.x] = s[threadIdx.x] - v;  // exclusive
}

__global__ void k_offsets(const int* __restrict__ deg, const int* __restrict__ bsum,
                          int* __restrict__ off, float* __restrict__ dinv, int n, int E) {
    __shared__ int s[THREADS];
    int i = blockIdx.x * THREADS + threadIdx.x;
    int v = (i < n) ? deg[i] : 0;
    s[threadIdx.x] = v;
    __syncthreads();
    for (int o = 1; o < THREADS; o <<= 1) {
        int t = (threadIdx.x >= (unsigned)o) ? s[threadIdx.x - o] : 0;
        __syncthreads();
        s[threadIdx.x] += t;
        __syncthreads();
    }
    if (i < n) {
        off[i] = bsum[blockIdx.x] + s[threadIdx.x] - v;
        dinv[i] = rsqrtf((float)v + 1.0f);
        if (i == n - 1) off[n] = E;
    }
}

// one fire-and-forget scattered 4B store per edge; no atomics
__global__ void k_bucket(const int* __restrict__ src, const int* __restrict__ dst,
                         const int* __restrict__ rank, const int* __restrict__ off,
                         int* __restrict__ csr_src, int E) {
    int e = blockIdx.x * blockDim.x + threadIdx.x;
    if (e >= E) return;
    csr_src[off[dst[e]] + rank[e]] = src[e];
}

// ---------- tiled GEMM (fp32 X): C'[r,c] = (X@W)[r,c] * dinv[r] -> bf16 ----------
__global__ __launch_bounds__(THREADS) void
k_gemm_f32(const float* __restrict__ X, const float* __restrict__ W,
           const float* __restrict__ dinv, ushort* __restrict__ C, int n, int fin) {
    __shared__ float Xs[KC][68];
    __shared__ float Ws[KC][64];
    int tid = threadIdx.x;
    int r0  = blockIdx.x * 64;
    int tx4 = (tid & 15) * 4;
    int ty4 = (tid >> 4) * 4;
    int sxr = tid >> 2, sxk = (tid & 3) * 4;
    int swk = tid >> 4, swc = (tid & 15) * 4;
    int xrow = r0 + sxr; if (xrow >= n) xrow = n - 1;
    const float* xptr = X + (size_t)xrow * fin;
    float4 acc0 = {0,0,0,0}, acc1 = {0,0,0,0}, acc2 = {0,0,0,0}, acc3 = {0,0,0,0};
    for (int kc = 0; kc < fin; kc += KC) {
        float4 xa = *(const float4*)(xptr + kc + sxk);
        float4 xb = *(const float4*)(xptr + kc + 16 + sxk);
        float4 wa = *(const float4*)(W + (size_t)(kc + swk) * 64 + swc);
        float4 wb = *(const float4*)(W + (size_t)(kc + swk + 16) * 64 + swc);
        __syncthreads();
        Xs[sxk + 0][sxr] = xa.x; Xs[sxk + 1][sxr] = xa.y;
        Xs[sxk + 2][sxr] = xa.z; Xs[sxk + 3][sxr] = xa.w;
        Xs[16 + sxk + 0][sxr] = xb.x; Xs[16 + sxk + 1][sxr] = xb.y;
        Xs[16 + sxk + 2][sxr] = xb.z; Xs[16 + sxk + 3][sxr] = xb.w;
        *(float4*)&Ws[swk][swc]      = wa;
        *(float4*)&Ws[swk + 16][swc] = wb;
        __syncthreads();
        #pragma unroll 8
        for (int k = 0; k < KC; ++k) {
            float4 a = *(const float4*)&Xs[k][ty4];
            float4 b = *(const float4*)&Ws[k][tx4];
            acc0.x = fmaf(a.x, b.x, acc0.x); acc0.y = fmaf(a.x, b.y, acc0.y);
            acc0.z = fmaf(a.x, b.z, acc0.z); acc0.w = fmaf(a.x, b.w, acc0.w);
            acc1.x = fmaf(a.y, b.x, acc1.x); acc1.y = fmaf(a.y, b.y, acc1.y);
            acc1.z = fmaf(a.y, b.z, acc1.z); acc1.w = fmaf(a.y, b.w, acc1.w);
            acc2.x = fmaf(a.z, b.x, acc2.x); acc2.y = fmaf(a.z, b.y, acc2.y);
            acc2.z = fmaf(a.z, b.z, acc2.z); acc2.w = fmaf(a.z, b.w, acc2.w);
            acc3.x = fmaf(a.w, b.x, acc3.x); acc3.y = fmaf(a.w, b.y, acc3.y);
            acc3.z = fmaf(a.w, b.z, acc3.z); acc3.w = fmaf(a.w, b.w, acc3.w);
        }
    }
    int row = r0 + ty4;
    #pragma unroll
    for (int r = 0; r < 4; ++r) {
        if (row + r >= n) break;
        float dn = dinv[row + r];
        float4 a = r == 0 ? acc0 : r == 1 ? acc1 : r == 2 ? acc2 : acc3;
        ushort4 o;
        o.x = f2bf(a.x * dn); o.y = f2bf(a.y * dn);
        o.z = f2bf(a.z * dn); o.w = f2bf(a.w * dn);
        *(ushort4*)(C + (size_t)(row + r) * 64 + tx4) = o;
    }
}

// ---------- tiled GEMM (bf16 X): C' = (X@W)*dinv -> bf16 ----------
__global__ __launch_bounds__(THREADS) void
k_gemm_bf16(const ushort* __restrict__ X, const float* __restrict__ W,
            const float* __restrict__ dinv, ushort* __restrict__ C, int n, int fin) {
    __shared__ float Xs[KC][68];
    __shared__ float Ws[KC][64];
    int tid = threadIdx.x;
    int r0  = blockIdx.x * 64;
    int tx4 = (tid & 15) * 4;
    int ty4 = (tid >> 4) * 4;
    int sxr = tid >> 2, sk8 = (tid & 3) * 8;
    int swk = tid >> 4, swc = (tid & 15) * 4;
    int xrow = r0 + sxr; if (xrow >= n) xrow = n - 1;
    const ushort* xptr = X + (size_t)xrow * fin;
    float4 acc0 = {0,0,0,0}, acc1 = {0,0,0,0}, acc2 = {0,0,0,0}, acc3 = {0,0,0,0};
    for (int kc = 0; kc < fin; kc += KC) {
        uint4 xv = *(const uint4*)(xptr + kc + sk8);
        float4 wa = *(const float4*)(W + (size_t)(kc + swk) * 64 + swc);
        float4 wb = *(const float4*)(W + (size_t)(kc + swk + 16) * 64 + swc);
        __syncthreads();
        Xs[sk8 + 0][sxr] = bflo(xv.x); Xs[sk8 + 1][sxr] = bfhi(xv.x);
        Xs[sk8 + 2][sxr] = bflo(xv.y); Xs[sk8 + 3][sxr] = bfhi(xv.y);
        Xs[sk8 + 4][sxr] = bflo(xv.z); Xs[sk8 + 5][sxr] = bfhi(xv.z);
        Xs[sk8 + 6][sxr] = bflo(xv.w); Xs[sk8 + 7][sxr] = bfhi(xv.w);
        *(float4*)&Ws[swk][swc]      = wa;
        *(float4*)&Ws[swk + 16][swc] = wb;
        __syncthreads();
        #pragma unroll 8
        for (int k = 0; k < KC; ++k) {
            float4 a = *(const float4*)&Xs[k][ty4];
            float4 b = *(const float4*)&Ws[k][tx4];
            acc0.x = fmaf(a.x, b.x, acc0.x); acc0.y = fmaf(a.x, b.y, acc0.y);
            acc0.z = fmaf(a.x, b.z, acc0.z); acc0.w = fmaf(a.x, b.w, acc0.w);
            acc1.x = fmaf(a.y, b.x, acc1.x); acc1.y = fmaf(a.y, b.y, acc1.y);
            acc1.z = fmaf(a.y, b.z, acc1.z); acc1.w = fmaf(a.y, b.w, acc1.w);
            acc2.x = fmaf(a.z, b.x, acc2.x); acc2.y = fmaf(a.z, b.y, acc2.y);
            acc2.z = fmaf(a.z, b.z, acc2.z); acc2.w = fmaf(a.z, b.w, acc2.w);
            acc3.x = fmaf(a.w, b.x, acc3.x); acc3.y = fmaf(a.w, b.y, acc3.y);
            acc3.z = fmaf(a.w, b.z, acc3.z); acc3.w = fmaf(a.w, b.w, acc3.w);
        }
    }
    int row = r0 + ty4;
    #pragma unroll
    for (int r = 0; r < 4; ++r) {
        if (row + r >= n) break;
        float dn = dinv[row + r];
        float4 a = r == 0 ? acc0 : r == 1 ? acc1 : r == 2 ? acc2 : acc3;
        ushort4 o;
        o.x = f2bf(a.x * dn); o.y = f2bf(a.y * dn);
        o.z = f2bf(a.z * dn); o.w = f2bf(a.w * dn);
        *(ushort4*)(C + (size_t)(row + r) * 64 + tx4) = o;
    }
}

// ---------- MLP gather core: wave = 1 node, 4 rows per mem instruction ----------
// lane = (g,q): g = lane>>4 (row slot), q = lane&15 (col quad, cols 4q..4q+3).
// Each uint2 load fetches 4 bf16 cols of one row; a wave instruction covers 4
// rows; 2x unroll + dual accumulators = 8 rows in flight.
__device__ inline float4 gather_sum(const ushort* __restrict__ H,
                                    const int* __restrict__ csr,
                                    int node, int j, int end, int g, int q) {
    float4 A0 = {0,0,0,0}, A1 = {0,0,0,0};
    if (g == 0) {  // self row joins slot 0
        uint2 sv = *(const uint2*)(H + ((size_t)node << 6) + q * 4);
        A0.x += bflo(sv.x); A0.y += bfhi(sv.x);
        A0.z += bflo(sv.y); A0.w += bfhi(sv.y);
    }
    for (; j + 8 <= end; j += 8) {
        int s0 = csr[j + g];
        int s1 = csr[j + 4 + g];
        uint2 v0 = *(const uint2*)(H + ((size_t)s0 << 6) + q * 4);
        uint2 v1 = *(const uint2*)(H + ((size_t)s1 << 6) + q * 4);
        A0.x += bflo(v0.x); A0.y += bfhi(v0.x);
        A0.z += bflo(v0.y); A0.w += bfhi(v0.y);
        A1.x += bflo(v1.x); A1.y += bfhi(v1.x);
        A1.z += bflo(v1.y); A1.w += bfhi(v1.y);
    }
    if (j + 4 <= end) {
        int s0 = csr[j + g];
        uint2 v0 = *(const uint2*)(H + ((size_t)s0 << 6) + q * 4);
        A0.x += bflo(v0.x); A0.y += bfhi(v0.x);
        A0.z += bflo(v0.y); A0.w += bfhi(v0.y);
        j += 4;
    }
    if (g < end - j) {
        int s1 = csr[j + g];
        uint2 v1 = *(const uint2*)(H + ((size_t)s1 << 6) + q * 4);
        A1.x += bflo(v1.x); A1.y += bfhi(v1.x);
        A1.z += bflo(v1.y); A1.w += bfhi(v1.y);
    }
    float4 A;
    A.x = A0.x + A1.x; A.y = A0.y + A1.y;
    A.z = A0.z + A1.z; A.w = A0.w + A1.w;
    // reduce over the 4 row slots (lane bits 4,5)
    A.x += __shfl_xor(A.x, 16); A.x += __shfl_xor(A.x, 32);
    A.y += __shfl_xor(A.y, 16); A.y += __shfl_xor(A.y, 32);
    A.z += __shfl_xor(A.z, 16); A.z += __shfl_xor(A.z, 32);
    A.w += __shfl_xor(A.w, 16); A.w += __shfl_xor(A.w, 32);
    return A;
}

// ---------- layer-1: gather + self + bias + ReLU -> bf16 ----------
__global__ void k_gcn_gather(const ushort* __restrict__ H, const int* __restrict__ csr,
                             const int* __restrict__ off, const float* __restrict__ dinv,
                             const float* __restrict__ b, ushort* __restrict__ out, int n) {
    int t = blockIdx.x * blockDim.x + threadIdx.x;
    int node = t >> 6;
    if (node >= n) return;
    int lane = threadIdx.x & 63;
    int g = lane >> 4, q = lane & 15;
    float4 A = gather_sum(H, csr, node, off[node], off[node + 1], g, q);
    if (g == 0) {
        float dn = dinv[node];
        float4 bb = *(const float4*)(b + q * 4);
        float v0 = A.x * dn + bb.x, v1 = A.y * dn + bb.y;
        float v2 = A.z * dn + bb.z, v3 = A.w * dn + bb.w;
        ushort4 o;
        o.x = f2bf(v0 > 0.f ? v0 : 0.f); o.y = f2bf(v1 > 0.f ? v1 : 0.f);
        o.z = f2bf(v2 > 0.f ? v2 : 0.f); o.w = f2bf(v3 > 0.f ? v3 : 0.f);
        *(ushort4*)(out + ((size_t)node << 6) + q * 4) = o;
    }
}

// ---------- layer-2: gather + ReLU + fused FC(64->16) + 16-dim pool scatter ----
__global__ void k_gcn_gather_fc(const ushort* __restrict__ H, const int* __restrict__ csr,
                                const int* __restrict__ off, const float* __restrict__ dinv,
                                const float* __restrict__ b, const float* __restrict__ Wfc,
                                const int* __restrict__ dict, float* __restrict__ pool16,
                                int n) {
    __shared__ float wt[16 * 65];     // Wfc transposed [r][c], pad 65
    __shared__ float hrow[4][64];
    int tid = threadIdx.x;
    for (int i = tid; i < 64 * 16; i += THREADS) {
        int cc = i >> 4, r = i & 15;
        wt[r * 65 + cc] = Wfc[i];     // Wfc[cc*16 + r]
    }
    __syncthreads();
    int t = blockIdx.x * blockDim.x + tid;
    int node = t >> 6;
    int lane = tid & 63;
    int g = lane >> 4, q = lane & 15;
    int nl = tid >> 6;
    if (node < n) {
        float4 A = gather_sum(H, csr, node, off[node], off[node + 1], g, q);
        if (g == 0) {
            float dn = dinv[node];
            float4 bb = *(const float4*)(b + q * 4);
            float4 v;
            v.x = A.x * dn + bb.x; v.y = A.y * dn + bb.y;
            v.z = A.z * dn + bb.z; v.w = A.w * dn + bb.w;
            v.x = v.x > 0.f ? v.x : 0.f; v.y = v.y > 0.f ? v.y : 0.f;
            v.z = v.z > 0.f ? v.z : 0.f; v.w = v.w > 0.f ? v.w : 0.f;
            *(float4*)&hrow[nl][q * 4] = v;    // same-wave LDS: no barrier needed
        }
        // FC partials: lane (g,r): g covers cols [g*16, g*16+16)
        int r = q;
        float p = 0.f;
        #pragma unroll
        for (int i = 0; i < 16; ++i) {
            int cc = g * 16 + i;
            p = fmaf(hrow[nl][cc], wt[r * 65 + cc], p);
        }
        p += __shfl_xor(p, 16);
        p += __shfl_xor(p, 32);
        if (g == 0)
            atomicAdd(&pool16[(size_t)dict[node] * 16 + r], p);
    }
}

__global__ void k_cnt(const int* __restrict__ dict, float* __restrict__ cnt, int n) {
    int i = blockIdx.x * blockDim.x + threadIdx.x;
    if (i < n) atomicAdd(&cnt[dict[i]], 1.0f);
}

// ---------- mean + bias + log_softmax over 16 classes ----------
__global__ void k_final16(const float* __restrict__ pool16, const float* __restrict__ cnt,
                          const float* __restrict__ bfc, float* __restrict__ out, int n) {
    int tid = threadIdx.x;
    int nl = tid >> 4, lane = tid & 15;
    int node = blockIdx.x * 16 + nl;
    if (node >= n) return;
    float inv = 1.0f / fmaxf(cnt[node], 1.0f);
    float acc = pool16[(size_t)node * 16 + lane] * inv + bfc[lane];
    float m = acc;
    for (int o = 8; o; o >>= 1) m = fmaxf(m, __shfl_xor(m, o, 16));
    float ex = __expf(acc - m);
    float s = ex;
    for (int o = 8; o; o >>= 1) s += __shfl_xor(s, o, 16);
    out[(size_t)node * 16 + lane] = acc - m - __logf(s);
}

extern "C" void kernel_launch(void* const* d_in, const int* in_sizes, int n_in,
                              void* d_out, int out_size, void* d_ws, size_t ws_size,
                              hipStream_t stream) {
    const float* x    = (const float*)d_in[0];
    const int*   ei   = (const int*)d_in[1];
    const int*   dict = (const int*)d_in[2];
    const float* W1   = (const float*)d_in[3];
    const float* b1   = (const float*)d_in[4];
    const float* W2   = (const float*)d_in[5];
    const float* b2   = (const float*)d_in[6];
    const float* Wfc  = (const float*)d_in[7];
    const float* bfc  = (const float*)d_in[8];

    const int N  = in_sizes[2];          // 100000
    const int E  = in_sizes[1] / 2;      // 1600000
    const int IN = in_sizes[0] / N;      // 128
    const int* src = ei;
    const int* dst = ei + E;

    // workspace layout (~46 MB)
    ushort* bufA   = (ushort*)d_ws;                // N*64 bf16
    ushort* bufB   = bufA + (size_t)N * 64;        // N*64 bf16
    float* dinv    = (float*)(bufB + (size_t)N * 64);  // N
    int*   deg     = (int*)(dinv + N);             // N
    float* cnt     = (float*)(deg + N);            // N
    int*   off     = (int*)(cnt + N);              // N+1
    int*   bsum    = off + (N + 1);                // 512
    int*   rank    = bsum + 512;                   // E
    int*   csr     = rank + E;                     // E
    float* pool16  = (float*)(csr + E);            // N*16

    const int gN    = (N + THREADS - 1) / THREADS;          // 391
    const int gE    = (E + THREADS - 1) / THREADS;          // 6250
    const int gNE   = (N * 64 + THREADS - 1) / THREADS;     // 25000
    const int gTile = (N + 63) / 64;                        // 1563
    const int gRows = (N + 15) / 16;                        // 6250

    // CSR build (once; reused by both layers)
    hipMemsetAsync(deg, 0, (size_t)N * sizeof(int), stream);
    hipMemsetAsync(cnt, 0, (size_t)N * sizeof(float), stream);
    hipMemsetAsync(pool16, 0, (size_t)N * 16 * sizeof(float), stream);
    k_deg<<<gE, THREADS, 0, stream>>>(dst, deg, rank, E);
    k_bsum<<<gN, THREADS, 0, stream>>>(deg, bsum, N);
    k_bscan<<<1, 512, 0, stream>>>(bsum, gN);
    k_offsets<<<gN, THREADS, 0, stream>>>(deg, bsum, off, dinv, N, E);
    k_bucket<<<gE, THREADS, 0, stream>>>(src, dst, rank, off, csr, E);

    // layer 1: A = bf16((x@W1)*dinv) ; B = bf16(relu(dn*(sum+self)+b1))
    k_gemm_f32<<<gTile, THREADS, 0, stream>>>(x, W1, dinv, bufA, N, IN);
    k_gcn_gather<<<gNE, THREADS, 0, stream>>>(bufA, csr, off, dinv, b1, bufB, N);

    // layer 2: A = bf16((B@W2)*dinv) ; fused gather+ReLU+FC+pool
    k_gemm_bf16<<<gTile, THREADS, 0, stream>>>(bufB, W2, dinv, bufA, N, 64);
    k_gcn_gather_fc<<<gNE, THREADS, 0, stream>>>(bufA, csr, off, dinv, b2, Wfc,
                                                 dict, pool16, N);
    k_cnt<<<gN, THREADS, 0, stream>>>(dict, cnt, N);

    // mean + bias + log_softmax
    k_final16<<<gRows, THREADS, 0, stream>>>(pool16, cnt, bfc, (float*)d_out, N);
}

// Round 9
// 355.278 us; speedup vs baseline: 1.7692x; 1.0733x over previous
//
#include <hip/hip_runtime.h>

#define THREADS 256
#define KC 32

// ---- bf16 helpers ----
__device__ inline ushort f2bf(float v) {
    union { float f; unsigned u; } a; a.f = v;
    unsigned r = a.u + 0x7fff + ((a.u >> 16) & 1);
    return (ushort)(r >> 16);
}
__device__ inline unsigned pack2(float a, float b) {
    return (unsigned)f2bf(a) | ((unsigned)f2bf(b) << 16);
}
__device__ inline float bflo(unsigned v) {
    union { unsigned u; float f; } a; a.u = v << 16; return a.f;
}
__device__ inline float bfhi(unsigned v) {
    union { unsigned u; float f; } a; a.u = v & 0xffff0000u; return a.f;
}

// ---------- F1: fused [GEMM1 unscaled -> bf16] + [deg + rank] ----------
__global__ __launch_bounds__(THREADS) void
k_f1(const float* __restrict__ X, const float* __restrict__ W,
     ushort* __restrict__ C, int n, int fin,
     const int* __restrict__ dst, int* __restrict__ deg, int* __restrict__ rank,
     int E, int nGemm, int nDeg) {
    int tid = threadIdx.x;
    if ((int)blockIdx.x >= nGemm) {
        // ---- deg role: grid-stride edge histogram with returned rank ----
        int stride = nDeg * THREADS;
        for (int e = ((int)blockIdx.x - nGemm) * THREADS + tid; e < E; e += stride)
            rank[e] = atomicAdd(&deg[dst[e]], 1);
        return;
    }
    // ---- GEMM role: C[r,c] = (X@W)[r,c] -> bf16 (unscaled) ----
    __shared__ float Xs[KC][68];
    __shared__ float Ws[KC][64];
    int r0  = blockIdx.x * 64;
    int tx4 = (tid & 15) * 4;
    int ty4 = (tid >> 4) * 4;
    int sxr = tid >> 2, sxk = (tid & 3) * 4;
    int swk = tid >> 4, swc = (tid & 15) * 4;
    int xrow = r0 + sxr; if (xrow >= n) xrow = n - 1;
    const float* xptr = X + (size_t)xrow * fin;
    float4 acc0 = {0,0,0,0}, acc1 = {0,0,0,0}, acc2 = {0,0,0,0}, acc3 = {0,0,0,0};
    for (int kc = 0; kc < fin; kc += KC) {
        float4 xa = *(const float4*)(xptr + kc + sxk);
        float4 xb = *(const float4*)(xptr + kc + 16 + sxk);
        float4 wa = *(const float4*)(W + (size_t)(kc + swk) * 64 + swc);
        float4 wb = *(const float4*)(W + (size_t)(kc + swk + 16) * 64 + swc);
        __syncthreads();
        Xs[sxk + 0][sxr] = xa.x; Xs[sxk + 1][sxr] = xa.y;
        Xs[sxk + 2][sxr] = xa.z; Xs[sxk + 3][sxr] = xa.w;
        Xs[16 + sxk + 0][sxr] = xb.x; Xs[16 + sxk + 1][sxr] = xb.y;
        Xs[16 + sxk + 2][sxr] = xb.z; Xs[16 + sxk + 3][sxr] = xb.w;
        *(float4*)&Ws[swk][swc]      = wa;
        *(float4*)&Ws[swk + 16][swc] = wb;
        __syncthreads();
        #pragma unroll 8
        for (int k = 0; k < KC; ++k) {
            float4 a = *(const float4*)&Xs[k][ty4];
            float4 b = *(const float4*)&Ws[k][tx4];
            acc0.x = fmaf(a.x, b.x, acc0.x); acc0.y = fmaf(a.x, b.y, acc0.y);
            acc0.z = fmaf(a.x, b.z, acc0.z); acc0.w = fmaf(a.x, b.w, acc0.w);
            acc1.x = fmaf(a.y, b.x, acc1.x); acc1.y = fmaf(a.y, b.y, acc1.y);
            acc1.z = fmaf(a.y, b.z, acc1.z); acc1.w = fmaf(a.y, b.w, acc1.w);
            acc2.x = fmaf(a.z, b.x, acc2.x); acc2.y = fmaf(a.z, b.y, acc2.y);
            acc2.z = fmaf(a.z, b.z, acc2.z); acc2.w = fmaf(a.z, b.w, acc2.w);
            acc3.x = fmaf(a.w, b.x, acc3.x); acc3.y = fmaf(a.w, b.y, acc3.y);
            acc3.z = fmaf(a.w, b.z, acc3.z); acc3.w = fmaf(a.w, b.w, acc3.w);
        }
    }
    int row = r0 + ty4;
    #pragma unroll
    for (int r = 0; r < 4; ++r) {
        if (row + r >= n) break;
        float4 a = r == 0 ? acc0 : r == 1 ? acc1 : r == 2 ? acc2 : acc3;
        ushort4 o;
        o.x = f2bf(a.x); o.y = f2bf(a.y); o.z = f2bf(a.z); o.w = f2bf(a.w);
        *(ushort4*)(C + (size_t)(row + r) * 64 + tx4) = o;
    }
}

// ---------- scans ----------
__global__ void k_bsum(const int* __restrict__ deg, int* __restrict__ bsum, int n) {
    __shared__ int s[THREADS];
    int i = blockIdx.x * THREADS + threadIdx.x;
    s[threadIdx.x] = (i < n) ? deg[i] : 0;
    __syncthreads();
    for (int o = THREADS / 2; o; o >>= 1) {
        if (threadIdx.x < o) s[threadIdx.x] += s[threadIdx.x + o];
        __syncthreads();
    }
    if (threadIdx.x == 0) bsum[blockIdx.x] = s[0];
}

// single block of 512; nb <= 512 (nb = 391 here)
__global__ void k_bscan(int* __restrict__ bsum, int nb) {
    __shared__ int s[512];
    int v = (threadIdx.x < nb) ? bsum[threadIdx.x] : 0;
    s[threadIdx.x] = v;
    __syncthreads();
    for (int o = 1; o < 512; o <<= 1) {
        int t = (threadIdx.x >= (unsigned)o) ? s[threadIdx.x - o] : 0;
        __syncthreads();
        s[threadIdx.x] += t;
        __syncthreads();
    }
    if (threadIdx.x < nb) bsum[threadIdx.x] = s[threadIdx.x] - v;  // exclusive
}

__global__ void k_offsets(const int* __restrict__ deg, const int* __restrict__ bsum,
                          int* __restrict__ off, float* __restrict__ dinv, int n, int E) {
    __shared__ int s[THREADS];
    int i = blockIdx.x * THREADS + threadIdx.x;
    int v = (i < n) ? deg[i] : 0;
    s[threadIdx.x] = v;
    __syncthreads();
    for (int o = 1; o < THREADS; o <<= 1) {
        int t = (threadIdx.x >= (unsigned)o) ? s[threadIdx.x - o] : 0;
        __syncthreads();
        s[threadIdx.x] += t;
        __syncthreads();
    }
    if (i < n) {
        off[i] = bsum[blockIdx.x] + s[threadIdx.x] - v;
        dinv[i] = rsqrtf((float)v + 1.0f);
        if (i == n - 1) off[n] = E;
    }
}

// ---------- F2: fused [bucket] + [scale bufA by dinv] + [cnt] ----------
__global__ void k_f2(const int* __restrict__ src, const int* __restrict__ dst,
                     const int* __restrict__ rank, const int* __restrict__ off,
                     int* __restrict__ csr, int E,
                     ushort* __restrict__ A, const float* __restrict__ dinv, int n,
                     const int* __restrict__ dict, float* __restrict__ cnt,
                     int nBucket, int nScale, int nCnt) {
    int bid = blockIdx.x;
    int tid = threadIdx.x;
    if (bid < nBucket) {
        int stride = nBucket * THREADS;
        for (int e = bid * THREADS + tid; e < E; e += stride)
            csr[off[dst[e]] + rank[e]] = src[e];
    } else if (bid < nBucket + nScale) {
        int t = (bid - nBucket) * THREADS + tid;    // one uint4 (8 bf16) per thread
        if (t < n * 8) {
            float dn = dinv[t >> 3];
            uint4 v = *(const uint4*)(A + (size_t)t * 8);
            uint4 o;
            o.x = pack2(bflo(v.x) * dn, bfhi(v.x) * dn);
            o.y = pack2(bflo(v.y) * dn, bfhi(v.y) * dn);
            o.z = pack2(bflo(v.z) * dn, bfhi(v.z) * dn);
            o.w = pack2(bflo(v.w) * dn, bfhi(v.w) * dn);
            *(uint4*)(A + (size_t)t * 8) = o;
        }
    } else {
        int stride = nCnt * THREADS;
        for (int i = (bid - nBucket - nScale) * THREADS + tid; i < n; i += stride)
            atomicAdd(&cnt[dict[i]], 1.0f);
    }
}

// ---------- tiled GEMM (bf16 X): C' = (X@W)*dinv -> bf16 ----------
__global__ __launch_bounds__(THREADS) void
k_gemm_bf16(const ushort* __restrict__ X, const float* __restrict__ W,
            const float* __restrict__ dinv, ushort* __restrict__ C, int n, int fin) {
    __shared__ float Xs[KC][68];
    __shared__ float Ws[KC][64];
    int tid = threadIdx.x;
    int r0  = blockIdx.x * 64;
    int tx4 = (tid & 15) * 4;
    int ty4 = (tid >> 4) * 4;
    int sxr = tid >> 2, sk8 = (tid & 3) * 8;
    int swk = tid >> 4, swc = (tid & 15) * 4;
    int xrow = r0 + sxr; if (xrow >= n) xrow = n - 1;
    const ushort* xptr = X + (size_t)xrow * fin;
    float4 acc0 = {0,0,0,0}, acc1 = {0,0,0,0}, acc2 = {0,0,0,0}, acc3 = {0,0,0,0};
    for (int kc = 0; kc < fin; kc += KC) {
        uint4 xv = *(const uint4*)(xptr + kc + sk8);
        float4 wa = *(const float4*)(W + (size_t)(kc + swk) * 64 + swc);
        float4 wb = *(const float4*)(W + (size_t)(kc + swk + 16) * 64 + swc);
        __syncthreads();
        Xs[sk8 + 0][sxr] = bflo(xv.x); Xs[sk8 + 1][sxr] = bfhi(xv.x);
        Xs[sk8 + 2][sxr] = bflo(xv.y); Xs[sk8 + 3][sxr] = bfhi(xv.y);
        Xs[sk8 + 4][sxr] = bflo(xv.z); Xs[sk8 + 5][sxr] = bfhi(xv.z);
        Xs[sk8 + 6][sxr] = bflo(xv.w); Xs[sk8 + 7][sxr] = bfhi(xv.w);
        *(float4*)&Ws[swk][swc]      = wa;
        *(float4*)&Ws[swk + 16][swc] = wb;
        __syncthreads();
        #pragma unroll 8
        for (int k = 0; k < KC; ++k) {
            float4 a = *(const float4*)&Xs[k][ty4];
            float4 b = *(const float4*)&Ws[k][tx4];
            acc0.x = fmaf(a.x, b.x, acc0.x); acc0.y = fmaf(a.x, b.y, acc0.y);
            acc0.z = fmaf(a.x, b.z, acc0.z); acc0.w = fmaf(a.x, b.w, acc0.w);
            acc1.x = fmaf(a.y, b.x, acc1.x); acc1.y = fmaf(a.y, b.y, acc1.y);
            acc1.z = fmaf(a.y, b.z, acc1.z); acc1.w = fmaf(a.y, b.w, acc1.w);
            acc2.x = fmaf(a.z, b.x, acc2.x); acc2.y = fmaf(a.z, b.y, acc2.y);
            acc2.z = fmaf(a.z, b.z, acc2.z); acc2.w = fmaf(a.z, b.w, acc2.w);
            acc3.x = fmaf(a.w, b.x, acc3.x); acc3.y = fmaf(a.w, b.y, acc3.y);
            acc3.z = fmaf(a.w, b.z, acc3.z); acc3.w = fmaf(a.w, b.w, acc3.w);
        }
    }
    int row = r0 + ty4;
    #pragma unroll
    for (int r = 0; r < 4; ++r) {
        if (row + r >= n) break;
        float dn = dinv[row + r];
        float4 a = r == 0 ? acc0 : r == 1 ? acc1 : r == 2 ? acc2 : acc3;
        ushort4 o;
        o.x = f2bf(a.x * dn); o.y = f2bf(a.y * dn);
        o.z = f2bf(a.z * dn); o.w = f2bf(a.w * dn);
        *(ushort4*)(C + (size_t)(row + r) * 64 + tx4) = o;
    }
}

// ---------- MLP gather core: wave = 1 node, 8 rows per mem instruction ----------
// lane = (g,q): g = lane>>3 (row slot 0..7), q = lane&7 (col octet: cols 8q..8q+7).
// uint4 load = 8 bf16 cols of one row; one wave instruction covers 8 rows;
// 2x unroll = 16 rows in flight (matches avg degree).
__device__ inline void gather_sum8(const ushort* __restrict__ H,
                                   const int* __restrict__ csr,
                                   int node, int j, int end, int g, int q,
                                   float4& R0, float4& R1) {
    float4 A0 = {0,0,0,0}, B0 = {0,0,0,0}, A1 = {0,0,0,0}, B1 = {0,0,0,0};
    if (g == 0) {  // self row joins slot 0
        uint4 sv = *(const uint4*)(H + ((size_t)node << 6) + q * 8);
        A0.x += bflo(sv.x); A0.y += bfhi(sv.x); A0.z += bflo(sv.y); A0.w += bfhi(sv.y);
        B0.x += bflo(sv.z); B0.y += bfhi(sv.z); B0.z += bflo(sv.w); B0.w += bfhi(sv.w);
    }
    for (; j + 16 <= end; j += 16) {
        int s0 = csr[j + g];
        int s1 = csr[j + 8 + g];
        uint4 v0 = *(const uint4*)(H + ((size_t)s0 << 6) + q * 8);
        uint4 v1 = *(const uint4*)(H + ((size_t)s1 << 6) + q * 8);
        A0.x += bflo(v0.x); A0.y += bfhi(v0.x); A0.z += bflo(v0.y); A0.w += bfhi(v0.y);
        B0.x += bflo(v0.z); B0.y += bfhi(v0.z); B0.z += bflo(v0.w); B0.w += bfhi(v0.w);
        A1.x += bflo(v1.x); A1.y += bfhi(v1.x); A1.z += bflo(v1.y); A1.w += bfhi(v1.y);
        B1.x += bflo(v1.z); B1.y += bfhi(v1.z); B1.z += bflo(v1.w); B1.w += bfhi(v1.w);
    }
    if (j + 8 <= end) {
        int s0 = csr[j + g];
        uint4 v0 = *(const uint4*)(H + ((size_t)s0 << 6) + q * 8);
        A0.x += bflo(v0.x); A0.y += bfhi(v0.x); A0.z += bflo(v0.y); A0.w += bfhi(v0.y);
        B0.x += bflo(v0.z); B0.y += bfhi(v0.z); B0.z += bflo(v0.w); B0.w += bfhi(v0.w);
        j += 8;
    }
    if (g < end - j) {
        int s1 = csr[j + g];
        uint4 v1 = *(const uint4*)(H + ((size_t)s1 << 6) + q * 8);
        A1.x += bflo(v1.x); A1.y += bfhi(v1.x); A1.z += bflo(v1.y); A1.w += bfhi(v1.y);
        B1.x += bflo(v1.z); B1.y += bfhi(v1.z); B1.z += bflo(v1.w); B1.w += bfhi(v1.w);
    }
    R0.x = A0.x + A1.x; R0.y = A0.y + A1.y; R0.z = A0.z + A1.z; R0.w = A0.w + A1.w;
    R1.x = B0.x + B1.x; R1.y = B0.y + B1.y; R1.z = B0.z + B1.z; R1.w = B0.w + B1.w;
    // reduce over the 8 row slots (lane bits 3,4,5)
    #pragma unroll
    for (int o = 8; o <= 32; o <<= 1) {
        R0.x += __shfl_xor(R0.x, o); R0.y += __shfl_xor(R0.y, o);
        R0.z += __shfl_xor(R0.z, o); R0.w += __shfl_xor(R0.w, o);
        R1.x += __shfl_xor(R1.x, o); R1.y += __shfl_xor(R1.y, o);
        R1.z += __shfl_xor(R1.z, o); R1.w += __shfl_xor(R1.w, o);
    }
}

// ---------- layer-1: gather + self + bias + ReLU -> bf16 ----------
__global__ void k_gcn_gather(const ushort* __restrict__ H, const int* __restrict__ csr,
                             const int* __restrict__ off, const float* __restrict__ dinv,
                             const float* __restrict__ b, ushort* __restrict__ out, int n) {
    int t = blockIdx.x * blockDim.x + threadIdx.x;
    int node = t >> 6;
    if (node >= n) return;
    int lane = threadIdx.x & 63;
    int g = lane >> 3, q = lane & 7;
    float4 R0, R1;
    gather_sum8(H, csr, node, off[node], off[node + 1], g, q, R0, R1);
    if (g == 0) {
        float dn = dinv[node];
        float4 b0 = *(const float4*)(b + q * 8);
        float4 b1 = *(const float4*)(b + q * 8 + 4);
        float v0 = R0.x * dn + b0.x, v1 = R0.y * dn + b0.y;
        float v2 = R0.z * dn + b0.z, v3 = R0.w * dn + b0.w;
        float v4 = R1.x * dn + b1.x, v5 = R1.y * dn + b1.y;
        float v6 = R1.z * dn + b1.z, v7 = R1.w * dn + b1.w;
        uint4 o;
        o.x = pack2(v0 > 0.f ? v0 : 0.f, v1 > 0.f ? v1 : 0.f);
        o.y = pack2(v2 > 0.f ? v2 : 0.f, v3 > 0.f ? v3 : 0.f);
        o.z = pack2(v4 > 0.f ? v4 : 0.f, v5 > 0.f ? v5 : 0.f);
        o.w = pack2(v6 > 0.f ? v6 : 0.f, v7 > 0.f ? v7 : 0.f);
        *(uint4*)(out + ((size_t)node << 6) + q * 8) = o;
    }
}

// ---------- layer-2: gather + ReLU + fused FC(64->16) + 16-dim pool scatter ----
__global__ void k_gcn_gather_fc(const ushort* __restrict__ H, const int* __restrict__ csr,
                                const int* __restrict__ off, const float* __restrict__ dinv,
                                const float* __restrict__ b, const float* __restrict__ Wfc,
                                const int* __restrict__ dict, float* __restrict__ pool16,
                                int n) {
    __shared__ float wt[16 * 65];     // Wfc transposed [r][c], pad 65
    __shared__ float hrow[4][64];
    int tid = threadIdx.x;
    for (int i = tid; i < 64 * 16; i += THREADS) {
        int cc = i >> 4, r = i & 15;
        wt[r * 65 + cc] = Wfc[i];     // Wfc[cc*16 + r]
    }
    __syncthreads();
    int t = blockIdx.x * blockDim.x + tid;
    int node = t >> 6;
    int lane = tid & 63;
    int g = lane >> 3, q = lane & 7;
    int nl = tid >> 6;
    if (node < n) {
        float4 R0, R1;
        gather_sum8(H, csr, node, off[node], off[node + 1], g, q, R0, R1);
        if (g == 0) {
            float dn = dinv[node];
            float4 b0 = *(const float4*)(b + q * 8);
            float4 b1 = *(const float4*)(b + q * 8 + 4);
            float4 v0, v1;
            v0.x = R0.x * dn + b0.x; v0.y = R0.y * dn + b0.y;
            v0.z = R0.z * dn + b0.z; v0.w = R0.w * dn + b0.w;
            v1.x = R1.x * dn + b1.x; v1.y = R1.y * dn + b1.y;
            v1.z = R1.z * dn + b1.z; v1.w = R1.w * dn + b1.w;
            v0.x = v0.x > 0.f ? v0.x : 0.f; v0.y = v0.y > 0.f ? v0.y : 0.f;
            v0.z = v0.z > 0.f ? v0.z : 0.f; v0.w = v0.w > 0.f ? v0.w : 0.f;
            v1.x = v1.x > 0.f ? v1.x : 0.f; v1.y = v1.y > 0.f ? v1.y : 0.f;
            v1.z = v1.z > 0.f ? v1.z : 0.f; v1.w = v1.w > 0.f ? v1.w : 0.f;
            *(float4*)&hrow[nl][q * 8]     = v0;   // same-wave LDS RAW: hw-ordered
            *(float4*)&hrow[nl][q * 8 + 4] = v1;
        }
        // FC partials: lane (g2,r): g2 covers cols [g2*16, g2*16+16)
        int g2 = lane >> 4, r = lane & 15;
        float p = 0.f;
        #pragma unroll
        for (int i = 0; i < 16; ++i) {
            int cc = g2 * 16 + i;
            p = fmaf(hrow[nl][cc], wt[r * 65 + cc], p);
        }
        p += __shfl_xor(p, 16);
        p += __shfl_xor(p, 32);
        if (g2 == 0)
            atomicAdd(&pool16[(size_t)dict[node] * 16 + r], p);
    }
}

// ---------- mean + bias + log_softmax over 16 classes ----------
__global__ void k_final16(const float* __restrict__ pool16, const float* __restrict__ cnt,
                          const float* __restrict__ bfc, float* __restrict__ out, int n) {
    int tid = threadIdx.x;
    int nl = tid >> 4, lane = tid & 15;
    int node = blockIdx.x * 16 + nl;
    if (node >= n) return;
    float inv = 1.0f / fmaxf(cnt[node], 1.0f);
    float acc = pool16[(size_t)node * 16 + lane] * inv + bfc[lane];
    float m = acc;
    for (int o = 8; o; o >>= 1) m = fmaxf(m, __shfl_xor(m, o, 16));
    float ex = __expf(acc - m);
    float s = ex;
    for (int o = 8; o; o >>= 1) s += __shfl_xor(s, o, 16);
    out[(size_t)node * 16 + lane] = acc - m - __logf(s);
}

extern "C" void kernel_launch(void* const* d_in, const int* in_sizes, int n_in,
                              void* d_out, int out_size, void* d_ws, size_t ws_size,
                              hipStream_t stream) {
    const float* x    = (const float*)d_in[0];
    const int*   ei   = (const int*)d_in[1];
    const int*   dict = (const int*)d_in[2];
    const float* W1   = (const float*)d_in[3];
    const float* b1   = (const float*)d_in[4];
    const float* W2   = (const float*)d_in[5];
    const float* b2   = (const float*)d_in[6];
    const float* Wfc  = (const float*)d_in[7];
    const float* bfc  = (const float*)d_in[8];

    const int N  = in_sizes[2];          // 100000
    const int E  = in_sizes[1] / 2;      // 1600000
    const int IN = in_sizes[0] / N;      // 128
    const int* src = ei;
    const int* dst = ei + E;

    // workspace layout (~46 MB)
    ushort* bufA   = (ushort*)d_ws;                // N*64 bf16
    ushort* bufB   = bufA + (size_t)N * 64;        // N*64 bf16
    float* dinv    = (float*)(bufB + (size_t)N * 64);  // N
    int*   deg     = (int*)(dinv + N);             // N
    float* cnt     = (float*)(deg + N);            // N
    int*   off     = (int*)(cnt + N);              // N+1
    int*   bsum    = off + (N + 1);                // 512
    int*   rank    = bsum + 512;                   // E
    int*   csr     = rank + E;                     // E
    float* pool16  = (float*)(csr + E);            // N*16

    const int gN     = (N + THREADS - 1) / THREADS;          // 391
    const int gNE    = (N * 64 + THREADS - 1) / THREADS;     // 25000
    const int gTile  = (N + 63) / 64;                        // 1563
    const int gRows  = (N + 15) / 16;                        // 6250
    const int nDeg   = 2048;
    const int nBkt   = 2048;
    const int nScale = (N * 8 + THREADS - 1) / THREADS;      // 3125
    const int nCnt   = 256;

    hipMemsetAsync(deg, 0, (size_t)N * sizeof(int), stream);
    hipMemsetAsync(cnt, 0, (size_t)N * sizeof(float), stream);
    hipMemsetAsync(pool16, 0, (size_t)N * 16 * sizeof(float), stream);

    // F1: GEMM1 (unscaled) + deg/rank in one dispatch
    k_f1<<<gTile + nDeg, THREADS, 0, stream>>>(x, W1, bufA, N, IN,
                                               dst, deg, rank, E, gTile, nDeg);
    // scans -> off, dinv
    k_bsum<<<gN, THREADS, 0, stream>>>(deg, bsum, N);
    k_bscan<<<1, 512, 0, stream>>>(bsum, gN);
    k_offsets<<<gN, THREADS, 0, stream>>>(deg, bsum, off, dinv, N, E);

    // F2: bucket + scale bufA by dinv + cnt in one dispatch
    k_f2<<<nBkt + nScale + nCnt, THREADS, 0, stream>>>(src, dst, rank, off, csr, E,
                                                       bufA, dinv, N, dict, cnt,
                                                       nBkt, nScale, nCnt);

    // layer 1 gather: B = bf16(relu(dn*(sum+self)+b1))
    k_gcn_gather<<<gNE, THREADS, 0, stream>>>(bufA, csr, off, dinv, b1, bufB, N);

    // layer 2: A = bf16((B@W2)*dinv) ; fused gather+ReLU+FC+pool
    k_gemm_bf16<<<gTile, THREADS, 0, stream>>>(bufB, W2, dinv, bufA, N, 64);
    k_gcn_gather_fc<<<gNE, THREADS, 0, stream>>>(bufA, csr, off, dinv, b2, Wfc,
                                                 dict, pool16, N);

    // mean + bias + log_softmax
    k_final16<<<gRows, THREADS, 0, stream>>>(pool16, cnt, bfc, (float*)d_out, N);
}